// Round 2
// baseline (994.891 us; speedup 1.0000x reference)
//
#include <hip/hip_runtime.h>
#include <math.h>

#define CHN_ 256
#define EPS_ 1e-5f

// LDS row strides (floats) - chosen for 16B alignment + bank-conflict freedom
#define XFS  260   // xf tile [16][260]
#define WINS 33    // in_proj  [128][33] (b32 reads, (33d+dd)%32=(d+dd)%32 distinct)
#define WXPS 68    // x_proj   [34][68]
#define WOUTS 68   // out_proj [32][68]
#define U2S  68    // u2 / y   [128][68]
#define BCS  36    // xdbl rows: [0,1]=dt, [4..19]=B, [20..35]=C (16B-aligned)

__device__ __forceinline__ float sigmoidf_(float v) { return 1.f / (1.f + __expf(-v)); }

__global__ __launch_bounds__(1024, 4) void spe_mamba_main(
    const float* __restrict__ x,
    const float* __restrict__ Win,    // (128,32)
    const float* __restrict__ convw,  // (64,1,4)
    const float* __restrict__ convb,  // (64,)
    const float* __restrict__ Wxp,    // (34,64)
    const float* __restrict__ dtw,    // (64,2)
    const float* __restrict__ dtb,    // (64,)
    const float* __restrict__ Alog,   // (64,16)
    const float* __restrict__ Dvec,   // (64,)
    const float* __restrict__ Wout,   // (32,64)
    float* __restrict__ pre,          // (B,256,64,64) pre-GN staging (= d_out)
    float* __restrict__ stats)        // ws: [B][4][2] sum/sumsq (atomic)
{
    __shared__ float xf_s[16 * XFS];      // also reused as out staging [p][m*8+t]
    __shared__ float Win_s[128 * WINS];
    __shared__ float Wxp_s[34 * WXPS];
    __shared__ float Wout_s[32 * WOUTS];
    __shared__ float u2_s[128 * U2S];     // u2, later y
    __shared__ float bc_s[128 * BCS];
    __shared__ float A_s[64 * 17];
    __shared__ float convw_s[64 * 5];
    __shared__ float convb_s[64];
    __shared__ float dtw_s[128];
    __shared__ float dtb_s[64];
    __shared__ float Dp_s[64];
    __shared__ float gred[8];             // [group][sum,sumsq]

    const int tid = threadIdx.x;
    const int bid = blockIdx.x;           // 1024 blocks, 16 px each
    const int b   = bid >> 8;             // 256 blocks per image
    const int hw0 = (bid & 255) << 4;     // pixel offset in 64x64 plane (16 consecutive w)

    // ---------------- phase 0: stage x tile + weights ----------------
    {
        const float* xb = x + ((b * CHN_) << 12) + hw0;
        const int pp = tid & 15, c0 = tid >> 4;
#pragma unroll
        for (int k = 0; k < 4; ++k) {
            const int c = c0 + (k << 6);
            xf_s[pp * XFS + c] = xb[(c << 12) + pp];
        }
        const int r5 = tid >> 5, c5 = tid & 31;
#pragma unroll
        for (int k = 0; k < 4; ++k) {
            const int r = r5 + (k << 5);
            Win_s[r * WINS + c5] = Win[(r << 5) + c5];
        }
        const int r6 = tid >> 6, c6 = tid & 63;
        Wxp_s[r6 * WXPS + c6] = Wxp[(r6 << 6) + c6];
        Wxp_s[(r6 + 16) * WXPS + c6] = Wxp[((r6 + 16) << 6) + c6];
        if (r6 < 2) Wxp_s[(r6 + 32) * WXPS + c6] = Wxp[((r6 + 32) << 6) + c6];
        Wout_s[r6 * WOUTS + c6] = Wout[(r6 << 6) + c6];
        Wout_s[(r6 + 16) * WOUTS + c6] = Wout[((r6 + 16) << 6) + c6];
        {
            const int rd = tid >> 4, s = tid & 15;
            A_s[rd * 17 + s] = -__expf(Alog[(rd << 4) + s]);  // A = -exp(A_log)
        }
        if (tid < 256) { const int dd = tid >> 2, kk = tid & 3; convw_s[dd * 5 + kk] = convw[(dd << 2) + kk]; }
        if (tid < 128) dtw_s[tid] = dtw[tid];
        if (tid < 64)  { convb_s[tid] = convb[tid]; dtb_s[tid] = dtb[tid]; Dp_s[tid] = Dvec[tid]; }
        if (tid < 8)   gred[tid] = 0.f;
    }
    __syncthreads();

    // ---------------- phase 1: in_proj (thread = (p=wave, d=lane)) ----------------
    const int p = tid >> 6;
    const int d = tid & 63;
    float uacc[8], zacc[8];
#pragma unroll
    for (int t = 0; t < 8; ++t) { uacc[t] = 0.f; zacc[t] = 0.f; }
#pragma unroll
    for (int dd4 = 0; dd4 < 8; ++dd4) {
        const float wu0 = Win_s[d * WINS + dd4 * 4 + 0];
        const float wu1 = Win_s[d * WINS + dd4 * 4 + 1];
        const float wu2 = Win_s[d * WINS + dd4 * 4 + 2];
        const float wu3 = Win_s[d * WINS + dd4 * 4 + 3];
        const float wz0 = Win_s[(64 + d) * WINS + dd4 * 4 + 0];
        const float wz1 = Win_s[(64 + d) * WINS + dd4 * 4 + 1];
        const float wz2 = Win_s[(64 + d) * WINS + dd4 * 4 + 2];
        const float wz3 = Win_s[(64 + d) * WINS + dd4 * 4 + 3];
#pragma unroll
        for (int t = 0; t < 8; ++t) {
            const float4 a4 = *reinterpret_cast<const float4*>(&xf_s[p * XFS + t * 32 + dd4 * 4]);
            uacc[t] = fmaf(a4.x, wu0, fmaf(a4.y, wu1, fmaf(a4.z, wu2, fmaf(a4.w, wu3, uacc[t]))));
            zacc[t] = fmaf(a4.x, wz0, fmaf(a4.y, wz1, fmaf(a4.z, wz2, fmaf(a4.w, wz3, zacc[t]))));
        }
    }

    // ---------------- phase 2: causal depthwise conv (T=8,K=4) + SiLU ----------------
    float u2r[8];
    {
        const float cw0 = convw_s[d * 5 + 0], cw1 = convw_s[d * 5 + 1];
        const float cw2 = convw_s[d * 5 + 2], cw3 = convw_s[d * 5 + 3];
        const float cb = convb_s[d];
#pragma unroll
        for (int t = 0; t < 8; ++t) {
            float acc = fmaf(uacc[t], cw3, cb);
            if (t >= 1) acc = fmaf(uacc[t - 1], cw2, acc);
            if (t >= 2) acc = fmaf(uacc[t - 2], cw1, acc);
            if (t >= 3) acc = fmaf(uacc[t - 3], cw0, acc);
            u2r[t] = acc * sigmoidf_(acc);
            u2_s[(p * 8 + t) * U2S + d] = u2r[t];
        }
    }
    __syncthreads();

    // ---------------- phase 3: x_proj -> dt,B,C (thread = (pt, j0)) ----------------
    {
        const int pt = tid >> 3, j0 = tid & 7;
        const float* u2row = &u2_s[pt * U2S];
        float acc[5] = {0.f, 0.f, 0.f, 0.f, 0.f};
#pragma unroll
        for (int e4 = 0; e4 < 16; ++e4) {
            const float4 a4 = *reinterpret_cast<const float4*>(&u2row[e4 * 4]);
#pragma unroll
            for (int k = 0; k < 5; ++k) {
                const int j = j0 + (k << 3);
                if (j < 34) {
                    const float4 w4 = *reinterpret_cast<const float4*>(&Wxp_s[j * WXPS + e4 * 4]);
                    acc[k] = fmaf(a4.x, w4.x, fmaf(a4.y, w4.y, fmaf(a4.z, w4.z, fmaf(a4.w, w4.w, acc[k]))));
                }
            }
        }
#pragma unroll
        for (int k = 0; k < 5; ++k) {
            const int j = j0 + (k << 3);
            if (j < 34) bc_s[pt * BCS + (j < 2 ? j : j + 2)] = acc[k];
        }
    }
    __syncthreads();

    // ---------------- phase 4: delta + selective scan + gate (thread = (p,d)) ----------------
    {
        float a_d[16];
#pragma unroll
        for (int s = 0; s < 16; ++s) a_d[s] = A_s[d * 17 + s];
        const float w0 = dtw_s[2 * d], w1 = dtw_s[2 * d + 1];
        const float bb = dtb_s[d], dpv = Dp_s[d];
        float h[16];
#pragma unroll
        for (int s = 0; s < 16; ++s) h[s] = 0.f;
#pragma unroll
        for (int t = 0; t < 8; ++t) {
            const float* bcrow = &bc_s[(p * 8 + t) * BCS];
            const float2 dt2 = *reinterpret_cast<const float2*>(&bcrow[0]);
            float dlt = fmaf(dt2.x, w0, fmaf(dt2.y, w1, bb));
            dlt = (dlt > 15.f) ? dlt : log1pf(__expf(dlt));   // softplus
            const float du = dlt * u2r[t];
            float yv = 0.f;
            // stream B/C from LDS (wave-uniform address -> broadcast, no conflict);
            // keeps live set small so nothing spills at 128 VGPRs.
#pragma unroll
            for (int q = 0; q < 4; ++q) {
                const float4 B4 = *reinterpret_cast<const float4*>(&bcrow[4 + (q << 2)]);
                const float4 C4 = *reinterpret_cast<const float4*>(&bcrow[20 + (q << 2)]);
                {
                    const float dA = __expf(dlt * a_d[q * 4 + 0]);
                    h[q * 4 + 0] = fmaf(h[q * 4 + 0], dA, du * B4.x);
                    yv = fmaf(h[q * 4 + 0], C4.x, yv);
                }
                {
                    const float dA = __expf(dlt * a_d[q * 4 + 1]);
                    h[q * 4 + 1] = fmaf(h[q * 4 + 1], dA, du * B4.y);
                    yv = fmaf(h[q * 4 + 1], C4.y, yv);
                }
                {
                    const float dA = __expf(dlt * a_d[q * 4 + 2]);
                    h[q * 4 + 2] = fmaf(h[q * 4 + 2], dA, du * B4.z);
                    yv = fmaf(h[q * 4 + 2], C4.z, yv);
                }
                {
                    const float dA = __expf(dlt * a_d[q * 4 + 3]);
                    h[q * 4 + 3] = fmaf(h[q * 4 + 3], dA, du * B4.w);
                    yv = fmaf(h[q * 4 + 3], C4.w, yv);
                }
            }
            const float zz = zacc[t];
            const float yfin = fmaf(u2r[t], dpv, yv) * (zz * sigmoidf_(zz));
            u2_s[(p * 8 + t) * U2S + d] = yfin;   // own slot: no cross-thread hazard
        }
    }
    __syncthreads();

    // ---------------- phase 6: out_proj + GN partials (thread = (p6,t6,m0)) ----------------
    {
        const int m0 = tid & 7;
        const int t6 = (tid >> 3) & 7;
        const int p6 = tid >> 6;
        const float* yrow = &u2_s[(p6 * 8 + t6) * U2S];
        float acc[4] = {0.f, 0.f, 0.f, 0.f};
#pragma unroll
        for (int e4 = 0; e4 < 16; ++e4) {
            const float4 a4 = *reinterpret_cast<const float4*>(&yrow[e4 * 4]);
#pragma unroll
            for (int k = 0; k < 4; ++k) {
                const float4 w4 = *reinterpret_cast<const float4*>(&Wout_s[(m0 + (k << 3)) * WOUTS + e4 * 4]);
                acc[k] = fmaf(a4.x, w4.x, fmaf(a4.y, w4.y, fmaf(a4.z, w4.z, fmaf(a4.w, w4.w, acc[k]))));
            }
        }
        float s1 = 0.f, s2 = 0.f;
#pragma unroll
        for (int k = 0; k < 4; ++k) {
            const float v = acc[k];
            s1 += v; s2 = fmaf(v, v, s2);
            xf_s[p6 * XFS + ((m0 + (k << 3)) << 3) + t6] = v;   // stage out as [p][m*8+t]
        }
        // lanes [0..15]->g0, [16..31]->g1, ... : group uniform per 16-lane cluster
#pragma unroll
        for (int off = 1; off < 16; off <<= 1) {
            s1 += __shfl_xor(s1, off);
            s2 += __shfl_xor(s2, off);
        }
        if ((tid & 15) == 0) {
            const int g = t6 >> 1;
            atomicAdd(&gred[g * 2], s1);
            atomicAdd(&gred[g * 2 + 1], s2);
        }
    }
    __syncthreads();

    // ---------------- phase 7: coalesced global write + stats flush ----------------
    {
        float* ob = pre + ((b * CHN_) << 12) + hw0;
        const int pp = tid & 15, c0 = tid >> 4;
#pragma unroll
        for (int k = 0; k < 4; ++k) {
            const int c = c0 + (k << 6);                       // chn = t*32+m
            ob[(c << 12) + pp] = xf_s[pp * XFS + ((c & 31) << 3) + (c >> 5)];
        }
        if (tid < 8) atomicAdd(&stats[(b << 3) + tid], gred[tid]);
    }
}

// GroupNorm + SiLU + residual, in-place on d_out
__global__ __launch_bounds__(256) void spe_gn(
    const float* __restrict__ x, float* __restrict__ io,
    const float* __restrict__ gnw, const float* __restrict__ gnb,
    const float* __restrict__ stats)
{
    const int i = blockIdx.x * 256 + threadIdx.x;   // float4 index, 1048576 total
    const int fi = i << 2;
    const int b = fi >> 20;
    const int chn = (fi >> 12) & 255;
    const int g = chn >> 6;
    const float inv = 1.f / 262144.f;
    const float s1 = stats[(b << 3) + (g << 1)];
    const float s2 = stats[(b << 3) + (g << 1) + 1];
    const float mean = s1 * inv;
    const float var = fmaf(-mean, mean, s2 * inv);
    const float rstd = rsqrtf(var + EPS_);
    const float gw = gnw[chn] * rstd;
    const float gb = gnb[chn];
    const float4 pv = reinterpret_cast<const float4*>(io)[i];
    const float4 xv = reinterpret_cast<const float4*>(x)[i];
    float4 r;
    {
        const float xn = fmaf(pv.x - mean, gw, gb); r.x = xv.x + xn * sigmoidf_(xn);
    }
    {
        const float xn = fmaf(pv.y - mean, gw, gb); r.y = xv.y + xn * sigmoidf_(xn);
    }
    {
        const float xn = fmaf(pv.z - mean, gw, gb); r.z = xv.z + xn * sigmoidf_(xn);
    }
    {
        const float xn = fmaf(pv.w - mean, gw, gb); r.w = xv.w + xn * sigmoidf_(xn);
    }
    reinterpret_cast<float4*>(io)[i] = r;
}

extern "C" void kernel_launch(void* const* d_in, const int* in_sizes, int n_in,
                              void* d_out, int out_size, void* d_ws, size_t ws_size,
                              hipStream_t stream) {
    const float* x     = (const float*)d_in[0];
    const float* Win   = (const float*)d_in[1];
    const float* convw = (const float*)d_in[2];
    const float* convb = (const float*)d_in[3];
    const float* Wxp   = (const float*)d_in[4];
    const float* dtwp  = (const float*)d_in[5];
    const float* dtbp  = (const float*)d_in[6];
    const float* Alog  = (const float*)d_in[7];
    const float* Dv    = (const float*)d_in[8];
    const float* Wout  = (const float*)d_in[9];
    const float* gnw   = (const float*)d_in[10];
    const float* gnb   = (const float*)d_in[11];
    float* out   = (float*)d_out;
    float* stats = (float*)d_ws;   // 32 floats

    hipMemsetAsync(stats, 0, 32 * sizeof(float), stream);
    spe_mamba_main<<<1024, 1024, 0, stream>>>(x, Win, convw, convb, Wxp, dtwp, dtbp,
                                              Alog, Dv, Wout, out, stats);
    spe_gn<<<4096, 256, 0, stream>>>(x, out, gnw, gnb, stats);
}

// Round 3
// 561.478 us; speedup vs baseline: 1.7719x; 1.7719x over previous
//
#include <hip/hip_runtime.h>
#include <math.h>

#define CHN_ 256
#define EPS_ 1e-5f

// LDS row strides (floats) - chosen for 16B alignment + bank-conflict freedom
#define XFS  260   // xf tile [16][260]
#define WINS 33    // in_proj  [128][33] (b32 reads, (33d+dd)%32=(d+dd)%32 distinct)
#define WXPS 68    // x_proj   [34][68]
#define WOUTS 68   // out_proj [32][68]
#define U2S  68    // u2 / y   [128][68]
#define BCS  36    // xdbl rows: [0,1]=dt, [4..19]=B, [20..35]=C (16B-aligned)
#define AS_  20    // A row stride (float4-aligned; 20d+4q covers all banks per 8 lanes)

__device__ __forceinline__ float sigmoidf_(float v) { return 1.f / (1.f + __expf(-v)); }

__global__ __launch_bounds__(1024) void spe_mamba_main(
    const float* __restrict__ x,
    const float* __restrict__ Win,    // (128,32)
    const float* __restrict__ convw,  // (64,1,4)
    const float* __restrict__ convb,  // (64,)
    const float* __restrict__ Wxp,    // (34,64)
    const float* __restrict__ dtw,    // (64,2)
    const float* __restrict__ dtb,    // (64,)
    const float* __restrict__ Alog,   // (64,16)
    const float* __restrict__ Dvec,   // (64,)
    const float* __restrict__ Wout,   // (32,64)
    float* __restrict__ pre,          // (B,256,64,64) pre-GN staging (= d_out)
    float* __restrict__ stats)        // ws: [B][4][2] sum/sumsq (atomic)
{
    __shared__ float xf_s[16 * XFS];      // also reused as out staging [p][m*8+t]
    __shared__ float Win_s[128 * WINS];
    __shared__ float Wxp_s[34 * WXPS];
    __shared__ float Wout_s[32 * WOUTS];
    __shared__ float u2_s[128 * U2S];     // u2, later y
    __shared__ float z_s[128 * U2S];      // raw z (pre-silu)
    __shared__ float bc_s[128 * BCS];
    __shared__ float A_s[64 * AS_];
    __shared__ float convw_s[64 * 5];
    __shared__ float convb_s[64];
    __shared__ float dtw_s[128];
    __shared__ float dtb_s[64];
    __shared__ float Dp_s[64];
    __shared__ float gred[8];             // [group][sum,sumsq]

    const int tid = threadIdx.x;
    const int bid = blockIdx.x;           // 1024 blocks, 16 px each
    const int b   = bid >> 8;             // 256 blocks per image
    const int hw0 = (bid & 255) << 4;     // pixel offset in 64x64 plane (16 consecutive w)

    // ---------------- phase 0: stage x tile + weights ----------------
    {
        const float* xb = x + ((b * CHN_) << 12) + hw0;
        const int pp = tid & 15, c0 = tid >> 4;
#pragma unroll
        for (int k = 0; k < 4; ++k) {
            const int c = c0 + (k << 6);
            xf_s[pp * XFS + c] = xb[(c << 12) + pp];
        }
        const int r5 = tid >> 5, c5 = tid & 31;
#pragma unroll
        for (int k = 0; k < 4; ++k) {
            const int r = r5 + (k << 5);
            Win_s[r * WINS + c5] = Win[(r << 5) + c5];
        }
        const int r6 = tid >> 6, c6 = tid & 63;
        Wxp_s[r6 * WXPS + c6] = Wxp[(r6 << 6) + c6];
        Wxp_s[(r6 + 16) * WXPS + c6] = Wxp[((r6 + 16) << 6) + c6];
        if (r6 < 2) Wxp_s[(r6 + 32) * WXPS + c6] = Wxp[((r6 + 32) << 6) + c6];
        Wout_s[r6 * WOUTS + c6] = Wout[(r6 << 6) + c6];
        Wout_s[(r6 + 16) * WOUTS + c6] = Wout[((r6 + 16) << 6) + c6];
        {
            const int rd = tid >> 4, s = tid & 15;
            A_s[rd * AS_ + s] = -__expf(Alog[(rd << 4) + s]);  // A = -exp(A_log)
        }
        if (tid < 256) { const int dd = tid >> 2, kk = tid & 3; convw_s[dd * 5 + kk] = convw[(dd << 2) + kk]; }
        if (tid < 128) dtw_s[tid] = dtw[tid];
        if (tid < 64)  { convb_s[tid] = convb[tid]; dtb_s[tid] = dtb[tid]; Dp_s[tid] = Dvec[tid]; }
        if (tid < 8)   gred[tid] = 0.f;
    }
    __syncthreads();

    // ---------------- phase 1: in_proj (thread = (p=wave, d=lane)) ----------------
    const int p = tid >> 6;
    const int d = tid & 63;
    {
        float uacc[8], zacc[8];
#pragma unroll
        for (int t = 0; t < 8; ++t) { uacc[t] = 0.f; zacc[t] = 0.f; }
#pragma unroll
        for (int dd4 = 0; dd4 < 8; ++dd4) {
            const float wu0 = Win_s[d * WINS + dd4 * 4 + 0];
            const float wu1 = Win_s[d * WINS + dd4 * 4 + 1];
            const float wu2 = Win_s[d * WINS + dd4 * 4 + 2];
            const float wu3 = Win_s[d * WINS + dd4 * 4 + 3];
            const float wz0 = Win_s[(64 + d) * WINS + dd4 * 4 + 0];
            const float wz1 = Win_s[(64 + d) * WINS + dd4 * 4 + 1];
            const float wz2 = Win_s[(64 + d) * WINS + dd4 * 4 + 2];
            const float wz3 = Win_s[(64 + d) * WINS + dd4 * 4 + 3];
#pragma unroll
            for (int t = 0; t < 8; ++t) {
                const float4 a4 = *reinterpret_cast<const float4*>(&xf_s[p * XFS + t * 32 + dd4 * 4]);
                uacc[t] = fmaf(a4.x, wu0, fmaf(a4.y, wu1, fmaf(a4.z, wu2, fmaf(a4.w, wu3, uacc[t]))));
                zacc[t] = fmaf(a4.x, wz0, fmaf(a4.y, wz1, fmaf(a4.z, wz2, fmaf(a4.w, wz3, zacc[t]))));
            }
        }

        // ---------------- phase 2: causal depthwise conv (T=8,K=4) + SiLU; stash u2,z in LDS ----------------
        const float cw0 = convw_s[d * 5 + 0], cw1 = convw_s[d * 5 + 1];
        const float cw2 = convw_s[d * 5 + 2], cw3 = convw_s[d * 5 + 3];
        const float cb = convb_s[d];
#pragma unroll
        for (int t = 0; t < 8; ++t) {
            float acc = fmaf(uacc[t], cw3, cb);
            if (t >= 1) acc = fmaf(uacc[t - 1], cw2, acc);
            if (t >= 2) acc = fmaf(uacc[t - 2], cw1, acc);
            if (t >= 3) acc = fmaf(uacc[t - 3], cw0, acc);
            const float u2v = acc * sigmoidf_(acc);
            u2_s[(p * 8 + t) * U2S + d] = u2v;
            z_s[(p * 8 + t) * U2S + d] = zacc[t];
        }
    }
    __syncthreads();

    // ---------------- phase 3: x_proj -> dt,B,C (thread = (pt, j0)) ----------------
    {
        const int pt = tid >> 3, j0 = tid & 7;
        const float* u2row = &u2_s[pt * U2S];
        float acc[5] = {0.f, 0.f, 0.f, 0.f, 0.f};
#pragma unroll
        for (int e4 = 0; e4 < 16; ++e4) {
            const float4 a4 = *reinterpret_cast<const float4*>(&u2row[e4 * 4]);
#pragma unroll
            for (int k = 0; k < 5; ++k) {
                const int j = j0 + (k << 3);
                if (j < 34) {
                    const float4 w4 = *reinterpret_cast<const float4*>(&Wxp_s[j * WXPS + e4 * 4]);
                    acc[k] = fmaf(a4.x, w4.x, fmaf(a4.y, w4.y, fmaf(a4.z, w4.z, fmaf(a4.w, w4.w, acc[k]))));
                }
            }
        }
#pragma unroll
        for (int k = 0; k < 5; ++k) {
            const int j = j0 + (k << 3);
            if (j < 34) bc_s[pt * BCS + (j < 2 ? j : j + 2)] = acc[k];
        }
    }
    __syncthreads();

    // ---------------- phase 4: delta + selective scan + gate (thread = (p,d)) ----------------
    // Live set kept ~40 VGPRs: only h[16] persistent; A/B/C/u2/z streamed from LDS.
    {
        const float w0 = dtw_s[2 * d], w1 = dtw_s[2 * d + 1];
        const float bb = dtb_s[d], dpv = Dp_s[d];
        float h[16];
#pragma unroll
        for (int s = 0; s < 16; ++s) h[s] = 0.f;
#pragma unroll
        for (int t = 0; t < 8; ++t) {
            const int row = p * 8 + t;
            const float* bcrow = &bc_s[row * BCS];
            const float2 dt2 = *reinterpret_cast<const float2*>(&bcrow[0]);
            float dlt = fmaf(dt2.x, w0, fmaf(dt2.y, w1, bb));
            dlt = (dlt > 15.f) ? dlt : log1pf(__expf(dlt));   // softplus
            const float u2v = u2_s[row * U2S + d];
            const float zz  = z_s[row * U2S + d];
            const float du = dlt * u2v;
            float yv = 0.f;
#pragma unroll
            for (int q = 0; q < 4; ++q) {
                const float4 A4 = *reinterpret_cast<const float4*>(&A_s[d * AS_ + (q << 2)]);
                const float4 B4 = *reinterpret_cast<const float4*>(&bcrow[4 + (q << 2)]);
                const float4 C4 = *reinterpret_cast<const float4*>(&bcrow[20 + (q << 2)]);
                {
                    const float dA = __expf(dlt * A4.x);
                    h[q * 4 + 0] = fmaf(h[q * 4 + 0], dA, du * B4.x);
                    yv = fmaf(h[q * 4 + 0], C4.x, yv);
                }
                {
                    const float dA = __expf(dlt * A4.y);
                    h[q * 4 + 1] = fmaf(h[q * 4 + 1], dA, du * B4.y);
                    yv = fmaf(h[q * 4 + 1], C4.y, yv);
                }
                {
                    const float dA = __expf(dlt * A4.z);
                    h[q * 4 + 2] = fmaf(h[q * 4 + 2], dA, du * B4.z);
                    yv = fmaf(h[q * 4 + 2], C4.z, yv);
                }
                {
                    const float dA = __expf(dlt * A4.w);
                    h[q * 4 + 3] = fmaf(h[q * 4 + 3], dA, du * B4.w);
                    yv = fmaf(h[q * 4 + 3], C4.w, yv);
                }
            }
            const float yfin = fmaf(u2v, dpv, yv) * (zz * sigmoidf_(zz));
            u2_s[row * U2S + d] = yfin;   // own slot, read-then-write by same thread only
        }
    }
    __syncthreads();

    // ---------------- phase 6: out_proj + GN partials (thread = (p6,t6,m0)) ----------------
    {
        const int m0 = tid & 7;
        const int t6 = (tid >> 3) & 7;
        const int p6 = tid >> 6;
        const float* yrow = &u2_s[(p6 * 8 + t6) * U2S];
        float acc[4] = {0.f, 0.f, 0.f, 0.f};
#pragma unroll
        for (int e4 = 0; e4 < 16; ++e4) {
            const float4 a4 = *reinterpret_cast<const float4*>(&yrow[e4 * 4]);
#pragma unroll
            for (int k = 0; k < 4; ++k) {
                const float4 w4 = *reinterpret_cast<const float4*>(&Wout_s[(m0 + (k << 3)) * WOUTS + e4 * 4]);
                acc[k] = fmaf(a4.x, w4.x, fmaf(a4.y, w4.y, fmaf(a4.z, w4.z, fmaf(a4.w, w4.w, acc[k]))));
            }
        }
        float s1 = 0.f, s2 = 0.f;
#pragma unroll
        for (int k = 0; k < 4; ++k) {
            const float v = acc[k];
            s1 += v; s2 = fmaf(v, v, s2);
            xf_s[p6 * XFS + ((m0 + (k << 3)) << 3) + t6] = v;   // stage out as [p][m*8+t]
        }
        // lanes [0..15]->g0, [16..31]->g1, ... : group uniform per 16-lane cluster
#pragma unroll
        for (int off = 1; off < 16; off <<= 1) {
            s1 += __shfl_xor(s1, off);
            s2 += __shfl_xor(s2, off);
        }
        if ((tid & 15) == 0) {
            const int g = t6 >> 1;
            atomicAdd(&gred[g * 2], s1);
            atomicAdd(&gred[g * 2 + 1], s2);
        }
    }
    __syncthreads();

    // ---------------- phase 7: coalesced global write + stats flush ----------------
    {
        float* ob = pre + ((b * CHN_) << 12) + hw0;
        const int pp = tid & 15, c0 = tid >> 4;
#pragma unroll
        for (int k = 0; k < 4; ++k) {
            const int c = c0 + (k << 6);                       // chn = t*32+m
            ob[(c << 12) + pp] = xf_s[pp * XFS + ((c & 31) << 3) + (c >> 5)];
        }
        if (tid < 8) atomicAdd(&stats[(b << 3) + tid], gred[tid]);
    }
}

// GroupNorm + SiLU + residual, in-place on d_out
__global__ __launch_bounds__(256) void spe_gn(
    const float* __restrict__ x, float* __restrict__ io,
    const float* __restrict__ gnw, const float* __restrict__ gnb,
    const float* __restrict__ stats)
{
    const int i = blockIdx.x * 256 + threadIdx.x;   // float4 index, 1048576 total
    const int fi = i << 2;
    const int b = fi >> 20;
    const int chn = (fi >> 12) & 255;
    const int g = chn >> 6;
    const float inv = 1.f / 262144.f;
    const float s1 = stats[(b << 3) + (g << 1)];
    const float s2 = stats[(b << 3) + (g << 1) + 1];
    const float mean = s1 * inv;
    const float var = fmaf(-mean, mean, s2 * inv);
    const float rstd = rsqrtf(var + EPS_);
    const float gw = gnw[chn] * rstd;
    const float gb = gnb[chn];
    const float4 pv = reinterpret_cast<const float4*>(io)[i];
    const float4 xv = reinterpret_cast<const float4*>(x)[i];
    float4 r;
    {
        const float xn = fmaf(pv.x - mean, gw, gb); r.x = xv.x + xn * sigmoidf_(xn);
    }
    {
        const float xn = fmaf(pv.y - mean, gw, gb); r.y = xv.y + xn * sigmoidf_(xn);
    }
    {
        const float xn = fmaf(pv.z - mean, gw, gb); r.z = xv.z + xn * sigmoidf_(xn);
    }
    {
        const float xn = fmaf(pv.w - mean, gw, gb); r.w = xv.w + xn * sigmoidf_(xn);
    }
    reinterpret_cast<float4*>(io)[i] = r;
}

extern "C" void kernel_launch(void* const* d_in, const int* in_sizes, int n_in,
                              void* d_out, int out_size, void* d_ws, size_t ws_size,
                              hipStream_t stream) {
    const float* x     = (const float*)d_in[0];
    const float* Win   = (const float*)d_in[1];
    const float* convw = (const float*)d_in[2];
    const float* convb = (const float*)d_in[3];
    const float* Wxp   = (const float*)d_in[4];
    const float* dtwp  = (const float*)d_in[5];
    const float* dtbp  = (const float*)d_in[6];
    const float* Alog  = (const float*)d_in[7];
    const float* Dv    = (const float*)d_in[8];
    const float* Wout  = (const float*)d_in[9];
    const float* gnw   = (const float*)d_in[10];
    const float* gnb   = (const float*)d_in[11];
    float* out   = (float*)d_out;
    float* stats = (float*)d_ws;   // 32 floats

    hipMemsetAsync(stats, 0, 32 * sizeof(float), stream);
    spe_mamba_main<<<1024, 1024, 0, stream>>>(x, Win, convw, convb, Wxp, dtwp, dtbp,
                                              Alog, Dv, Wout, out, stats);
    spe_gn<<<4096, 256, 0, stream>>>(x, out, gnw, gnb, stats);
}

// Round 4
// 208.428 us; speedup vs baseline: 4.7733x; 2.6939x over previous
//
#include <hip/hip_runtime.h>
#include <math.h>

#define CHN_ 256
#define EPS_ 1e-5f

// LDS row strides (floats) - chosen for 16B alignment + bank-conflict freedom
#define XFS  260   // xf tile [16][260]
#define WINS 33    // in_proj  [128][33] (b32 reads, (33d+dd)%32=(d+dd)%32 distinct)
#define WXPS 68    // x_proj   [34][68]
#define WOUTS 68   // out_proj [32][68]
#define U2S  68    // u2 / y   [128][68]
#define BCS  36    // xdbl rows: [0,1]=dt, [4..19]=B, [20..35]=C (16B-aligned)
#define AS_  20    // A row stride (float4-aligned)

__device__ __forceinline__ float sigmoidf_(float v) { return 1.f / (1.f + __expf(-v)); }

// amdgpu_waves_per_eu(4,4): pin allocator budget to 512/4 = 128 VGPRs.
// LDS (147 KB) already limits to 1 block/CU = 16 waves = 4 waves/EU, so
// this costs zero occupancy. Plain __launch_bounds__ heuristic targeted
// 8 waves/EU -> 64 VGPRs -> 1.4 GB of scratch spill traffic (rounds 1-3).
__global__ __launch_bounds__(1024) __attribute__((amdgpu_waves_per_eu(4, 4)))
void spe_mamba_main(
    const float* __restrict__ x,
    const float* __restrict__ Win,    // (128,32)
    const float* __restrict__ convw,  // (64,1,4)
    const float* __restrict__ convb,  // (64,)
    const float* __restrict__ Wxp,    // (34,64)
    const float* __restrict__ dtw,    // (64,2)
    const float* __restrict__ dtb,    // (64,)
    const float* __restrict__ Alog,   // (64,16)
    const float* __restrict__ Dvec,   // (64,)
    const float* __restrict__ Wout,   // (32,64)
    float* __restrict__ pre,          // (B,256,64,64) pre-GN staging (= d_out)
    float* __restrict__ stats)        // ws: [B][4][2] sum/sumsq (atomic)
{
    __shared__ float xf_s[16 * XFS];      // also reused as out staging [p][m*8+t]
    __shared__ float Win_s[128 * WINS];
    __shared__ float Wxp_s[34 * WXPS];
    __shared__ float Wout_s[32 * WOUTS];
    __shared__ float u2_s[128 * U2S];     // u2, later y
    __shared__ float z_s[128 * U2S];      // raw z (pre-silu)
    __shared__ float bc_s[128 * BCS];
    __shared__ float A_s[64 * AS_];
    __shared__ float convw_s[64 * 5];
    __shared__ float convb_s[64];
    __shared__ float dtw_s[128];
    __shared__ float dtb_s[64];
    __shared__ float Dp_s[64];
    __shared__ float gred[8];             // [group][sum,sumsq]

    const int tid = threadIdx.x;
    const int bid = blockIdx.x;           // 1024 blocks, 16 px each
    const int b   = bid >> 8;             // 256 blocks per image
    const int hw0 = (bid & 255) << 4;     // pixel offset in 64x64 plane (16 consecutive w)

    // ---------------- phase 0: stage x tile + weights ----------------
    {
        const float* xb = x + ((b * CHN_) << 12) + hw0;
        const int pp = tid & 15, c0 = tid >> 4;
#pragma unroll
        for (int k = 0; k < 4; ++k) {
            const int c = c0 + (k << 6);
            xf_s[pp * XFS + c] = xb[(c << 12) + pp];
        }
        const int r5 = tid >> 5, c5 = tid & 31;
#pragma unroll
        for (int k = 0; k < 4; ++k) {
            const int r = r5 + (k << 5);
            Win_s[r * WINS + c5] = Win[(r << 5) + c5];
        }
        const int r6 = tid >> 6, c6 = tid & 63;
        Wxp_s[r6 * WXPS + c6] = Wxp[(r6 << 6) + c6];
        Wxp_s[(r6 + 16) * WXPS + c6] = Wxp[((r6 + 16) << 6) + c6];
        if (r6 < 2) Wxp_s[(r6 + 32) * WXPS + c6] = Wxp[((r6 + 32) << 6) + c6];
        Wout_s[r6 * WOUTS + c6] = Wout[(r6 << 6) + c6];
        Wout_s[(r6 + 16) * WOUTS + c6] = Wout[((r6 + 16) << 6) + c6];
        {
            const int rd = tid >> 4, s = tid & 15;
            A_s[rd * AS_ + s] = -__expf(Alog[(rd << 4) + s]);  // A = -exp(A_log)
        }
        if (tid < 256) { const int dd = tid >> 2, kk = tid & 3; convw_s[dd * 5 + kk] = convw[(dd << 2) + kk]; }
        if (tid < 128) dtw_s[tid] = dtw[tid];
        if (tid < 64)  { convb_s[tid] = convb[tid]; dtb_s[tid] = dtb[tid]; Dp_s[tid] = Dvec[tid]; }
        if (tid < 8)   gred[tid] = 0.f;
    }
    __syncthreads();

    // ---------------- phase 1: in_proj (thread = (p=wave, d=lane)) ----------------
    const int p = tid >> 6;
    const int d = tid & 63;
    {
        float uacc[8], zacc[8];
#pragma unroll
        for (int t = 0; t < 8; ++t) { uacc[t] = 0.f; zacc[t] = 0.f; }
        // unroll 1: keep the scheduling region small so loads aren't hoisted
        // across iterations (live set stays ~45 regs).
#pragma unroll 1
        for (int dd4 = 0; dd4 < 8; ++dd4) {
            const float wu0 = Win_s[d * WINS + dd4 * 4 + 0];
            const float wu1 = Win_s[d * WINS + dd4 * 4 + 1];
            const float wu2 = Win_s[d * WINS + dd4 * 4 + 2];
            const float wu3 = Win_s[d * WINS + dd4 * 4 + 3];
            const float wz0 = Win_s[(64 + d) * WINS + dd4 * 4 + 0];
            const float wz1 = Win_s[(64 + d) * WINS + dd4 * 4 + 1];
            const float wz2 = Win_s[(64 + d) * WINS + dd4 * 4 + 2];
            const float wz3 = Win_s[(64 + d) * WINS + dd4 * 4 + 3];
#pragma unroll
            for (int t = 0; t < 8; ++t) {
                const float4 a4 = *reinterpret_cast<const float4*>(&xf_s[p * XFS + t * 32 + dd4 * 4]);
                uacc[t] = fmaf(a4.x, wu0, fmaf(a4.y, wu1, fmaf(a4.z, wu2, fmaf(a4.w, wu3, uacc[t]))));
                zacc[t] = fmaf(a4.x, wz0, fmaf(a4.y, wz1, fmaf(a4.z, wz2, fmaf(a4.w, wz3, zacc[t]))));
            }
        }

        // ---------------- phase 2: causal depthwise conv (T=8,K=4) + SiLU; stash u2,z in LDS ----------------
        const float cw0 = convw_s[d * 5 + 0], cw1 = convw_s[d * 5 + 1];
        const float cw2 = convw_s[d * 5 + 2], cw3 = convw_s[d * 5 + 3];
        const float cb = convb_s[d];
#pragma unroll
        for (int t = 0; t < 8; ++t) {
            float acc = fmaf(uacc[t], cw3, cb);
            if (t >= 1) acc = fmaf(uacc[t - 1], cw2, acc);
            if (t >= 2) acc = fmaf(uacc[t - 2], cw1, acc);
            if (t >= 3) acc = fmaf(uacc[t - 3], cw0, acc);
            const float u2v = acc * sigmoidf_(acc);
            u2_s[(p * 8 + t) * U2S + d] = u2v;
            z_s[(p * 8 + t) * U2S + d] = zacc[t];
        }
    }
    __syncthreads();

    // ---------------- phase 3: x_proj -> dt,B,C (thread = (pt, j0)) ----------------
    {
        const int pt = tid >> 3, j0 = tid & 7;
        const float* u2row = &u2_s[pt * U2S];
        float acc[5] = {0.f, 0.f, 0.f, 0.f, 0.f};
#pragma unroll 2
        for (int e4 = 0; e4 < 16; ++e4) {
            const float4 a4 = *reinterpret_cast<const float4*>(&u2row[e4 * 4]);
#pragma unroll
            for (int k = 0; k < 5; ++k) {
                const int j = j0 + (k << 3);
                if (j < 34) {
                    const float4 w4 = *reinterpret_cast<const float4*>(&Wxp_s[j * WXPS + e4 * 4]);
                    acc[k] = fmaf(a4.x, w4.x, fmaf(a4.y, w4.y, fmaf(a4.z, w4.z, fmaf(a4.w, w4.w, acc[k]))));
                }
            }
        }
#pragma unroll
        for (int k = 0; k < 5; ++k) {
            const int j = j0 + (k << 3);
            if (j < 34) bc_s[pt * BCS + (j < 2 ? j : j + 2)] = acc[k];
        }
    }
    __syncthreads();

    // ---------------- phase 4: delta + selective scan + gate (thread = (p,d)) ----------------
    // unroll 1 on t: only h[16] + ~30 transients live per region -> fits 128 VGPRs.
    {
        const float w0 = dtw_s[2 * d], w1 = dtw_s[2 * d + 1];
        const float bb = dtb_s[d], dpv = Dp_s[d];
        float h[16];
#pragma unroll
        for (int s = 0; s < 16; ++s) h[s] = 0.f;
#pragma unroll 1
        for (int t = 0; t < 8; ++t) {
            const int row = p * 8 + t;
            const float* bcrow = &bc_s[row * BCS];
            const float2 dt2 = *reinterpret_cast<const float2*>(&bcrow[0]);
            float dlt = fmaf(dt2.x, w0, fmaf(dt2.y, w1, bb));
            dlt = (dlt > 15.f) ? dlt : log1pf(__expf(dlt));   // softplus
            const float u2v = u2_s[row * U2S + d];
            const float zz  = z_s[row * U2S + d];
            const float du = dlt * u2v;
            float yv = 0.f;
#pragma unroll
            for (int q = 0; q < 4; ++q) {
                const float4 A4 = *reinterpret_cast<const float4*>(&A_s[d * AS_ + (q << 2)]);
                const float4 B4 = *reinterpret_cast<const float4*>(&bcrow[4 + (q << 2)]);
                const float4 C4 = *reinterpret_cast<const float4*>(&bcrow[20 + (q << 2)]);
                {
                    const float dA = __expf(dlt * A4.x);
                    h[q * 4 + 0] = fmaf(h[q * 4 + 0], dA, du * B4.x);
                    yv = fmaf(h[q * 4 + 0], C4.x, yv);
                }
                {
                    const float dA = __expf(dlt * A4.y);
                    h[q * 4 + 1] = fmaf(h[q * 4 + 1], dA, du * B4.y);
                    yv = fmaf(h[q * 4 + 1], C4.y, yv);
                }
                {
                    const float dA = __expf(dlt * A4.z);
                    h[q * 4 + 2] = fmaf(h[q * 4 + 2], dA, du * B4.z);
                    yv = fmaf(h[q * 4 + 2], C4.z, yv);
                }
                {
                    const float dA = __expf(dlt * A4.w);
                    h[q * 4 + 3] = fmaf(h[q * 4 + 3], dA, du * B4.w);
                    yv = fmaf(h[q * 4 + 3], C4.w, yv);
                }
            }
            const float yfin = fmaf(u2v, dpv, yv) * (zz * sigmoidf_(zz));
            u2_s[row * U2S + d] = yfin;   // own slot, read-then-write by same thread only
        }
    }
    __syncthreads();

    // ---------------- phase 6: out_proj + GN partials (thread = (p6,t6,m0)) ----------------
    {
        const int m0 = tid & 7;
        const int t6 = (tid >> 3) & 7;
        const int p6 = tid >> 6;
        const float* yrow = &u2_s[(p6 * 8 + t6) * U2S];
        float acc[4] = {0.f, 0.f, 0.f, 0.f};
#pragma unroll 2
        for (int e4 = 0; e4 < 16; ++e4) {
            const float4 a4 = *reinterpret_cast<const float4*>(&yrow[e4 * 4]);
#pragma unroll
            for (int k = 0; k < 4; ++k) {
                const float4 w4 = *reinterpret_cast<const float4*>(&Wout_s[(m0 + (k << 3)) * WOUTS + e4 * 4]);
                acc[k] = fmaf(a4.x, w4.x, fmaf(a4.y, w4.y, fmaf(a4.z, w4.z, fmaf(a4.w, w4.w, acc[k]))));
            }
        }
        float s1 = 0.f, s2 = 0.f;
#pragma unroll
        for (int k = 0; k < 4; ++k) {
            const float v = acc[k];
            s1 += v; s2 = fmaf(v, v, s2);
            xf_s[p6 * XFS + ((m0 + (k << 3)) << 3) + t6] = v;   // stage out as [p][m*8+t]
        }
        // lanes [0..15]->g0, [16..31]->g1, ... : group uniform per 16-lane cluster
#pragma unroll
        for (int off = 1; off < 16; off <<= 1) {
            s1 += __shfl_xor(s1, off);
            s2 += __shfl_xor(s2, off);
        }
        if ((tid & 15) == 0) {
            const int g = t6 >> 1;
            atomicAdd(&gred[g * 2], s1);
            atomicAdd(&gred[g * 2 + 1], s2);
        }
    }
    __syncthreads();

    // ---------------- phase 7: coalesced global write + stats flush ----------------
    {
        float* ob = pre + ((b * CHN_) << 12) + hw0;
        const int pp = tid & 15, c0 = tid >> 4;
#pragma unroll
        for (int k = 0; k < 4; ++k) {
            const int c = c0 + (k << 6);                       // chn = t*32+m
            ob[(c << 12) + pp] = xf_s[pp * XFS + ((c & 31) << 3) + (c >> 5)];
        }
        if (tid < 8) atomicAdd(&stats[(b << 3) + tid], gred[tid]);
    }
}

// GroupNorm + SiLU + residual, in-place on d_out
__global__ __launch_bounds__(256) void spe_gn(
    const float* __restrict__ x, float* __restrict__ io,
    const float* __restrict__ gnw, const float* __restrict__ gnb,
    const float* __restrict__ stats)
{
    const int i = blockIdx.x * 256 + threadIdx.x;   // float4 index, 1048576 total
    const int fi = i << 2;
    const int b = fi >> 20;
    const int chn = (fi >> 12) & 255;
    const int g = chn >> 6;
    const float inv = 1.f / 262144.f;
    const float s1 = stats[(b << 3) + (g << 1)];
    const float s2 = stats[(b << 3) + (g << 1) + 1];
    const float mean = s1 * inv;
    const float var = fmaf(-mean, mean, s2 * inv);
    const float rstd = rsqrtf(var + EPS_);
    const float gw = gnw[chn] * rstd;
    const float gb = gnb[chn];
    const float4 pv = reinterpret_cast<const float4*>(io)[i];
    const float4 xv = reinterpret_cast<const float4*>(x)[i];
    float4 r;
    {
        const float xn = fmaf(pv.x - mean, gw, gb); r.x = xv.x + xn * sigmoidf_(xn);
    }
    {
        const float xn = fmaf(pv.y - mean, gw, gb); r.y = xv.y + xn * sigmoidf_(xn);
    }
    {
        const float xn = fmaf(pv.z - mean, gw, gb); r.z = xv.z + xn * sigmoidf_(xn);
    }
    {
        const float xn = fmaf(pv.w - mean, gw, gb); r.w = xv.w + xn * sigmoidf_(xn);
    }
    reinterpret_cast<float4*>(io)[i] = r;
}

extern "C" void kernel_launch(void* const* d_in, const int* in_sizes, int n_in,
                              void* d_out, int out_size, void* d_ws, size_t ws_size,
                              hipStream_t stream) {
    const float* x     = (const float*)d_in[0];
    const float* Win   = (const float*)d_in[1];
    const float* convw = (const float*)d_in[2];
    const float* convb = (const float*)d_in[3];
    const float* Wxp   = (const float*)d_in[4];
    const float* dtwp  = (const float*)d_in[5];
    const float* dtbp  = (const float*)d_in[6];
    const float* Alog  = (const float*)d_in[7];
    const float* Dv    = (const float*)d_in[8];
    const float* Wout  = (const float*)d_in[9];
    const float* gnw   = (const float*)d_in[10];
    const float* gnb   = (const float*)d_in[11];
    float* out   = (float*)d_out;
    float* stats = (float*)d_ws;   // 32 floats

    hipMemsetAsync(stats, 0, 32 * sizeof(float), stream);
    spe_mamba_main<<<1024, 1024, 0, stream>>>(x, Win, convw, convb, Wxp, dtwp, dtbp,
                                              Alog, Dv, Wout, out, stats);
    spe_gn<<<4096, 256, 0, stream>>>(x, out, gnw, gnb, stats);
}

// Round 5
// 179.655 us; speedup vs baseline: 5.5378x; 1.1602x over previous
//
#include <hip/hip_runtime.h>
#include <math.h>

#define CHN_ 256
#define EPS_ 1e-5f

typedef __attribute__((ext_vector_type(8))) short short8_t;   // 8 bf16 (4 VGPRs)
typedef __attribute__((ext_vector_type(4))) float float4_t;   // MFMA C/D

__device__ __forceinline__ float sigmoidf_(float v) { return 1.f / (1.f + __expf(-v)); }

// f32 -> bf16 (RNE)
__device__ __forceinline__ ushort f2bf(float f) {
    union { float f; unsigned u; } v; v.f = f;
    unsigned r = v.u + 0x7FFFu + ((v.u >> 16) & 1u);
    return (ushort)(r >> 16);
}

// A1 swizzle: writer has px varying per lane (px = row>>3) -> xor px bits into
// the 16B-slot index.  ushort-index form: idx = (row*40 + k) ^ (((row>>3)&7)<<3).
__device__ __forceinline__ int a1_idx(int row, int k) {
    return (row * 40 + k) ^ (((row >> 3) & 7) << 3);
}

__global__ __launch_bounds__(1024) __attribute__((amdgpu_waves_per_eu(4, 4)))
void spe_mamba_main(
    const float* __restrict__ x,
    const float* __restrict__ Win,    // (128,32)
    const float* __restrict__ convw,  // (64,1,4)
    const float* __restrict__ convb,  // (64,)
    const float* __restrict__ Wxp,    // (34,64)
    const float* __restrict__ dtw,    // (64,2)
    const float* __restrict__ dtb,    // (64,)
    const float* __restrict__ Alog,   // (64,16)
    const float* __restrict__ Dvec,   // (64,)
    const float* __restrict__ Wout,   // (32,64)
    float* __restrict__ pre,          // (B,256,64,64) pre-GN staging (= d_out)
    float* __restrict__ stats)        // ws: [B][4][2] sum/sumsq (atomic)
{
    // bf16 MFMA operand buffers (strides chosen for <=2-way conflicts on b128 frag reads)
    __shared__ __align__(16) ushort A1s[128 * 40];   // xf bf16, swizzled
    __shared__ __align__(16) ushort W1s[128 * 40];   // in_proj_w bf16 [n][k]
    __shared__ __align__(16) ushort A2s[128 * 72];   // u2 bf16, later y bf16
    __shared__ __align__(16) ushort W2s[48 * 72];    // x_proj_w bf16, rows 34-47 zero
    __shared__ __align__(16) ushort W3s[32 * 72];    // out_proj_w bf16
    // f32 buffers
    __shared__ float uf_s[128 * 68];  // pre-conv u (GEMM1 C); later out staging [16][260]
    __shared__ float zf_s[128 * 68];  // z (GEMM1 C)
    __shared__ float bc_s[128 * 36];  // [0,1]=dt, [4..19]=B, [20..35]=C
    __shared__ float A_s[64 * 20];    // -exp(A_log), f32
    __shared__ float convw_s[64 * 5];
    __shared__ float convb_s[64];
    __shared__ float dtw_s[128];
    __shared__ float dtb_s[64];
    __shared__ float Dp_s[64];
    __shared__ float gred[8];         // [group][sum,sumsq]

    const int tid = threadIdx.x;
    const int bid = blockIdx.x;           // 1024 blocks, 16 px each
    const int b   = bid >> 8;
    const int hw0 = (bid & 255) << 4;
    const int w   = tid >> 6;             // wave 0..15
    const int l   = tid & 63;
    const int lr  = l & 15;
    const int kg  = l >> 4;

    // ---------------- P0: stage inputs (convert to bf16 where MFMA consumes) ----
    {
        const float* xb = x + ((b * CHN_) << 12) + hw0;
        const int pp = tid & 15, c0 = tid >> 4;
#pragma unroll
        for (int k = 0; k < 4; ++k) {
            const int c = c0 + (k << 6);
            const float v = xb[(c << 12) + pp];
            const int t = c >> 5, dm = c & 31;
            const int r = pp * 8 + t;
            A1s[a1_idx(r, dm)] = f2bf(v);
        }
        {   // W1: 128x32, 1024 float4 -> one per thread
            const int rw = tid >> 3, cp = (tid & 7) * 4;
            const float4 v = *reinterpret_cast<const float4*>(Win + rw * 32 + cp);
            W1s[rw * 40 + cp + 0] = f2bf(v.x);
            W1s[rw * 40 + cp + 1] = f2bf(v.y);
            W1s[rw * 40 + cp + 2] = f2bf(v.z);
            W1s[rw * 40 + cp + 3] = f2bf(v.w);
        }
        if (tid < 544) {  // W2 rows 0-33
            const int rw = tid >> 4, cp = (tid & 15) * 4;
            const float4 v = *reinterpret_cast<const float4*>(Wxp + rw * 64 + cp);
            W2s[rw * 72 + cp + 0] = f2bf(v.x);
            W2s[rw * 72 + cp + 1] = f2bf(v.y);
            W2s[rw * 72 + cp + 2] = f2bf(v.z);
            W2s[rw * 72 + cp + 3] = f2bf(v.w);
        }
        if (tid < 448) {  // W2 zero-pad rows 34-47 (cols 0-63)
            const int rw = 34 + (tid >> 5), cp = (tid & 31) * 2;
            W2s[rw * 72 + cp] = 0; W2s[rw * 72 + cp + 1] = 0;
        }
        if (tid < 512) {  // W3: 32x64
            const int rw = tid >> 4, cp = (tid & 15) * 4;
            const float4 v = *reinterpret_cast<const float4*>(Wout + rw * 64 + cp);
            W3s[rw * 72 + cp + 0] = f2bf(v.x);
            W3s[rw * 72 + cp + 1] = f2bf(v.y);
            W3s[rw * 72 + cp + 2] = f2bf(v.z);
            W3s[rw * 72 + cp + 3] = f2bf(v.w);
        }
        { const int rd = tid >> 4, s = tid & 15; A_s[rd * 20 + s] = -__expf(Alog[(rd << 4) + s]); }
        if (tid < 256) { convw_s[(tid >> 2) * 5 + (tid & 3)] = convw[tid]; }
        if (tid < 128) dtw_s[tid] = dtw[tid];
        if (tid < 64)  { convb_s[tid] = convb[tid]; dtb_s[tid] = dtb[tid]; Dp_s[tid] = Dvec[tid]; }
        if (tid < 8)   gred[tid] = 0.f;
    }
    __syncthreads();

    // ---------------- P1: GEMM1 (in_proj) via MFMA: C[128 tok][128] = A1 @ W1^T --
    {
        const int mt = w & 7, nb = (w >> 3) * 4;   // waves 0-7: u (n-tiles 0-3), 8-15: z
        const int r = mt * 16 + lr;
        const short8_t av = *reinterpret_cast<const short8_t*>(&A1s[a1_idx(r, kg * 8)]);
#pragma unroll
        for (int i = 0; i < 4; ++i) {
            const int n = (nb + i) * 16 + lr;
            const short8_t bv = *reinterpret_cast<const short8_t*>(&W1s[n * 40 + kg * 8]);
            float4_t acc = {0.f, 0.f, 0.f, 0.f};
            acc = __builtin_amdgcn_mfma_f32_16x16x32_bf16(av, bv, acc, 0, 0, 0);
#pragma unroll
            for (int rg = 0; rg < 4; ++rg) {
                const int row = mt * 16 + kg * 4 + rg;
                const int col = (nb + i) * 16 + lr;
                if (w < 8) uf_s[row * 68 + col]        = acc[rg];
                else       zf_s[row * 68 + (col - 64)] = acc[rg];
            }
        }
    }
    __syncthreads();

    // ---------------- P2: causal depthwise conv + SiLU (thread = (px=w, d=l)) ----
    float u2r[8];
    {
        const int px = w, d = l;
        const float cw0 = convw_s[d * 5 + 0], cw1 = convw_s[d * 5 + 1];
        const float cw2 = convw_s[d * 5 + 2], cw3 = convw_s[d * 5 + 3];
        const float cb = convb_s[d];
        float uu[8];
#pragma unroll
        for (int t = 0; t < 8; ++t) uu[t] = uf_s[(px * 8 + t) * 68 + d];
#pragma unroll
        for (int t = 0; t < 8; ++t) {
            float acc = fmaf(uu[t], cw3, cb);
            if (t >= 1) acc = fmaf(uu[t - 1], cw2, acc);
            if (t >= 2) acc = fmaf(uu[t - 2], cw1, acc);
            if (t >= 3) acc = fmaf(uu[t - 3], cw0, acc);
            const float u2v = acc * sigmoidf_(acc);
            u2r[t] = u2v;
            A2s[(px * 8 + t) * 72 + d] = f2bf(u2v);
        }
    }
    __syncthreads();

    // ---------------- P3: GEMM2 (x_proj) via MFMA: C[128][34] -------------------
    {
#pragma unroll 1
        for (int tt = w; tt < 24; tt += 16) {
            const int mt = tt & 7, nt = tt >> 3;
            const int r = mt * 16 + lr, n = nt * 16 + lr;
            const short8_t a0 = *reinterpret_cast<const short8_t*>(&A2s[r * 72 +  0 + kg * 8]);
            const short8_t a1 = *reinterpret_cast<const short8_t*>(&A2s[r * 72 + 32 + kg * 8]);
            const short8_t b0 = *reinterpret_cast<const short8_t*>(&W2s[n * 72 +  0 + kg * 8]);
            const short8_t b1 = *reinterpret_cast<const short8_t*>(&W2s[n * 72 + 32 + kg * 8]);
            float4_t acc = {0.f, 0.f, 0.f, 0.f};
            acc = __builtin_amdgcn_mfma_f32_16x16x32_bf16(a0, b0, acc, 0, 0, 0);
            acc = __builtin_amdgcn_mfma_f32_16x16x32_bf16(a1, b1, acc, 0, 0, 0);
            const int j = nt * 16 + lr;
            if (j < 34) {
                const int jj = (j < 2) ? j : j + 2;
#pragma unroll
                for (int rg = 0; rg < 4; ++rg)
                    bc_s[(mt * 16 + kg * 4 + rg) * 36 + jj] = acc[rg];
            }
        }
    }
    __syncthreads();

    // ---------------- P4: delta + selective scan + gate (thread = (p=w, d=l)) ----
    {
        const int p_ = w, d = l;
        float a_d[16];
#pragma unroll
        for (int q = 0; q < 4; ++q) {
            const float4 t4 = *reinterpret_cast<const float4*>(&A_s[d * 20 + q * 4]);
            a_d[q * 4 + 0] = t4.x; a_d[q * 4 + 1] = t4.y; a_d[q * 4 + 2] = t4.z; a_d[q * 4 + 3] = t4.w;
        }
        const float w0 = dtw_s[2 * d], w1 = dtw_s[2 * d + 1];
        const float bb = dtb_s[d], dpv = Dp_s[d];
        float h[16];
#pragma unroll
        for (int s = 0; s < 16; ++s) h[s] = 0.f;
#pragma unroll 1
        for (int t = 0; t < 8; ++t) {
            const int row = p_ * 8 + t;
            const float* bcrow = &bc_s[row * 36];
            const float2 dt2 = *reinterpret_cast<const float2*>(&bcrow[0]);
            float dlt = fmaf(dt2.x, w0, fmaf(dt2.y, w1, bb));
            dlt = (dlt > 15.f) ? dlt : log1pf(__expf(dlt));   // softplus
            const float u2v = u2r[t];
            const float zz = zf_s[row * 68 + d];
            const float du = dlt * u2v;
            float yv = 0.f;
#pragma unroll
            for (int q = 0; q < 4; ++q) {
                const float4 B4 = *reinterpret_cast<const float4*>(&bcrow[4 + (q << 2)]);
                const float4 C4 = *reinterpret_cast<const float4*>(&bcrow[20 + (q << 2)]);
                { const float dA = __expf(dlt * a_d[q * 4 + 0]); h[q*4+0] = fmaf(h[q*4+0], dA, du * B4.x); yv = fmaf(h[q*4+0], C4.x, yv); }
                { const float dA = __expf(dlt * a_d[q * 4 + 1]); h[q*4+1] = fmaf(h[q*4+1], dA, du * B4.y); yv = fmaf(h[q*4+1], C4.y, yv); }
                { const float dA = __expf(dlt * a_d[q * 4 + 2]); h[q*4+2] = fmaf(h[q*4+2], dA, du * B4.z); yv = fmaf(h[q*4+2], C4.z, yv); }
                { const float dA = __expf(dlt * a_d[q * 4 + 3]); h[q*4+3] = fmaf(h[q*4+3], dA, du * B4.w); yv = fmaf(h[q*4+3], C4.w, yv); }
            }
            const float yfin = fmaf(u2v, dpv, yv) * (zz * sigmoidf_(zz));
            A2s[row * 72 + d] = f2bf(yfin);   // y (bf16) for GEMM3; own slot
        }
    }
    __syncthreads();

    // ---------------- P5: GEMM3 (out_proj) via MFMA + GN partials + staging ------
    {
        const int mt = w & 7, nt = w >> 3;     // 16 tiles, 1 per wave
        const int r = mt * 16 + lr, n = nt * 16 + lr;
        const short8_t a0 = *reinterpret_cast<const short8_t*>(&A2s[r * 72 +  0 + kg * 8]);
        const short8_t a1 = *reinterpret_cast<const short8_t*>(&A2s[r * 72 + 32 + kg * 8]);
        const short8_t b0 = *reinterpret_cast<const short8_t*>(&W3s[n * 72 +  0 + kg * 8]);
        const short8_t b1 = *reinterpret_cast<const short8_t*>(&W3s[n * 72 + 32 + kg * 8]);
        float4_t acc = {0.f, 0.f, 0.f, 0.f};
        acc = __builtin_amdgcn_mfma_f32_16x16x32_bf16(a0, b0, acc, 0, 0, 0);
        acc = __builtin_amdgcn_mfma_f32_16x16x32_bf16(a1, b1, acc, 0, 0, 0);

        float sA = 0.f, s2A = 0.f, sB = 0.f, s2B = 0.f;
#pragma unroll
        for (int rg = 0; rg < 4; ++rg) {
            const int token = mt * 16 + kg * 4 + rg;
            const int px = token >> 3, t = token & 7;
            const int m = nt * 16 + lr;
            uf_s[px * 260 + m * 8 + t] = acc[rg];       // out staging [px][m*8+t]
            if (rg < 2) { sA += acc[rg]; s2A = fmaf(acc[rg], acc[rg], s2A); }
            else        { sB += acc[rg]; s2B = fmaf(acc[rg], acc[rg], s2B); }
        }
        // groups: kg even -> (g0,g1) via t=reg; kg odd -> (g2,g3) via t=reg+4.
        // reduce within parity class: xor {1,2,4,8} (same 16-cluster) + xor 32.
#pragma unroll
        for (int off = 1; off <= 8; off <<= 1) {
            sA += __shfl_xor(sA, off); s2A += __shfl_xor(s2A, off);
            sB += __shfl_xor(sB, off); s2B += __shfl_xor(s2B, off);
        }
        sA += __shfl_xor(sA, 32); s2A += __shfl_xor(s2A, 32);
        sB += __shfl_xor(sB, 32); s2B += __shfl_xor(s2B, 32);
        if (l == 0)  { atomicAdd(&gred[0], sA); atomicAdd(&gred[1], s2A);
                       atomicAdd(&gred[2], sB); atomicAdd(&gred[3], s2B); }
        if (l == 16) { atomicAdd(&gred[4], sA); atomicAdd(&gred[5], s2A);
                       atomicAdd(&gred[6], sB); atomicAdd(&gred[7], s2B); }
    }
    __syncthreads();

    // ---------------- P6: coalesced global write + stats flush -------------------
    {
        float* ob = pre + ((b * CHN_) << 12) + hw0;
        const int pp = tid & 15, c0 = tid >> 4;
#pragma unroll
        for (int k = 0; k < 4; ++k) {
            const int c = c0 + (k << 6);                       // chn = t*32+m
            ob[(c << 12) + pp] = uf_s[pp * 260 + ((c & 31) << 3) + (c >> 5)];
        }
        if (tid < 8) atomicAdd(&stats[(b << 3) + tid], gred[tid]);
    }
}

// GroupNorm + SiLU + residual, in-place on d_out (grid-stride x4 for ILP)
__global__ __launch_bounds__(256) void spe_gn(
    const float* __restrict__ x, float* __restrict__ io,
    const float* __restrict__ gnw, const float* __restrict__ gnb,
    const float* __restrict__ stats)
{
    const int i0 = blockIdx.x * 256 + threadIdx.x;   // float4 index
#pragma unroll
    for (int j = 0; j < 4; ++j) {
        const int i = i0 + j * 262144;
        const int fi = i << 2;
        const int b = fi >> 20;
        const int chn = (fi >> 12) & 255;
        const int g = chn >> 6;
        const float inv = 1.f / 262144.f;
        const float s1 = stats[(b << 3) + (g << 1)];
        const float s2 = stats[(b << 3) + (g << 1) + 1];
        const float mean = s1 * inv;
        const float var = fmaf(-mean, mean, s2 * inv);
        const float rstd = rsqrtf(var + EPS_);
        const float gw = gnw[chn] * rstd;
        const float gb = gnb[chn];
        const float4 pv = reinterpret_cast<const float4*>(io)[i];
        const float4 xv = reinterpret_cast<const float4*>(x)[i];
        float4 r;
        { const float xn = fmaf(pv.x - mean, gw, gb); r.x = xv.x + xn * sigmoidf_(xn); }
        { const float xn = fmaf(pv.y - mean, gw, gb); r.y = xv.y + xn * sigmoidf_(xn); }
        { const float xn = fmaf(pv.z - mean, gw, gb); r.z = xv.z + xn * sigmoidf_(xn); }
        { const float xn = fmaf(pv.w - mean, gw, gb); r.w = xv.w + xn * sigmoidf_(xn); }
        reinterpret_cast<float4*>(io)[i] = r;
    }
}

extern "C" void kernel_launch(void* const* d_in, const int* in_sizes, int n_in,
                              void* d_out, int out_size, void* d_ws, size_t ws_size,
                              hipStream_t stream) {
    const float* x     = (const float*)d_in[0];
    const float* Win   = (const float*)d_in[1];
    const float* convw = (const float*)d_in[2];
    const float* convb = (const float*)d_in[3];
    const float* Wxp   = (const float*)d_in[4];
    const float* dtwp  = (const float*)d_in[5];
    const float* dtbp  = (const float*)d_in[6];
    const float* Alog  = (const float*)d_in[7];
    const float* Dv    = (const float*)d_in[8];
    const float* Wout  = (const float*)d_in[9];
    const float* gnw   = (const float*)d_in[10];
    const float* gnb   = (const float*)d_in[11];
    float* out   = (float*)d_out;
    float* stats = (float*)d_ws;   // 32 floats

    hipMemsetAsync(stats, 0, 32 * sizeof(float), stream);
    spe_mamba_main<<<1024, 1024, 0, stream>>>(x, Win, convw, convb, Wxp, dtwp, dtbp,
                                              Alog, Dv, Wout, out, stats);
    spe_gn<<<1024, 256, 0, stream>>>(x, out, gnw, gnb, stats);
}